// Round 3
// baseline (528.488 us; speedup 1.0000x reference)
//
#include <hip/hip_runtime.h>

#define F 8
#define L 16
#define XN 8
#define YN 4
#define NS 3
#define BLK 256

// out layout: [L*N] (norm.T) followed by [YN*N] (out.T)
__global__ __launch_bounds__(256, 3) void eafnn_kernel(
    const float* __restrict__ inp,
    const float* __restrict__ x,
    const float* __restrict__ c,
    const float* __restrict__ b,
    const float* __restrict__ w,
    float* __restrict__ out,
    int n_total)
{
    // Polynomial form of the log2-domain Gaussian:
    //   k*d^2 = A*v^2 + B*v + C,  A = k = -log2(e)/(2b^2), B = -2kc, C = kc^2
    __shared__ __attribute__((aligned(16))) float s_A[F * L];
    __shared__ __attribute__((aligned(16))) float s_B[F * L];
    __shared__ __attribute__((aligned(16))) float s_Cp[F * L];
    __shared__ __attribute__((aligned(16))) float s_C0[L];
    __shared__ __attribute__((aligned(16))) float s_w[L * XN * YN];

    const int tid = threadIdx.x;
    if (tid < F * L) {
        float bb = b[tid], cc = c[tid];
        float k = -1.4426950408889634f / (2.0f * bb * bb);
        s_A[tid] = k;
        s_B[tid] = -2.0f * k * cc;
        s_Cp[tid] = k * cc * cc;
    }
    for (int i = tid; i < L * XN * YN; i += BLK) s_w[i] = w[i];
    __syncthreads();
    if (tid < L) {
        float a = 0.0f;
#pragma unroll
        for (int f = 0; f < F; ++f) a += s_Cp[f * L + tid];
        s_C0[tid] = a;
    }
    __syncthreads();

    const int n0 = blockIdx.x * (BLK * NS) + tid;

    int nn[NS];
#pragma unroll
    for (int s = 0; s < NS; ++s) {
        int n = n0 + s * BLK;
        nn[s] = (n < n_total) ? n : (n_total - 1);   // clamp loads; stores guarded
    }

    float sacc[NS][L];

    // ================= Phase A: membership accumulation =================
    {
        float fi[NS][F];
#pragma unroll
        for (int s = 0; s < NS; ++s) {
            const float4* ip = (const float4*)(inp + (size_t)nn[s] * F);
            float4 a0 = ip[0], a1 = ip[1];
            fi[s][0] = a0.x; fi[s][1] = a0.y; fi[s][2] = a0.z; fi[s][3] = a0.w;
            fi[s][4] = a1.x; fi[s][5] = a1.y; fi[s][6] = a1.z; fi[s][7] = a1.w;
        }

#pragma unroll
        for (int lq = 0; lq < L / 4; ++lq) {
            float4 cq = *(const float4*)&s_C0[lq * 4];
#pragma unroll
            for (int s = 0; s < NS; ++s) {
                sacc[s][lq * 4 + 0] = cq.x;
                sacc[s][lq * 4 + 1] = cq.y;
                sacc[s][lq * 4 + 2] = cq.z;
                sacc[s][lq * 4 + 3] = cq.w;
            }
        }

#pragma unroll
        for (int f = 0; f < F; ++f) {
            float v[NS], v2[NS];
#pragma unroll
            for (int s = 0; s < NS; ++s) { v[s] = fi[s][f]; v2[s] = v[s] * v[s]; }
#pragma unroll
            for (int lq = 0; lq < L / 4; ++lq) {
                float4 Aq = *(const float4*)&s_A[f * L + lq * 4];
                float4 Bq = *(const float4*)&s_B[f * L + lq * 4];
#pragma unroll
                for (int s = 0; s < NS; ++s) {
                    sacc[s][lq * 4 + 0] = fmaf(Aq.x, v2[s], fmaf(Bq.x, v[s], sacc[s][lq * 4 + 0]));
                    sacc[s][lq * 4 + 1] = fmaf(Aq.y, v2[s], fmaf(Bq.y, v[s], sacc[s][lq * 4 + 1]));
                    sacc[s][lq * 4 + 2] = fmaf(Aq.z, v2[s], fmaf(Bq.z, v[s], sacc[s][lq * 4 + 2]));
                    sacc[s][lq * 4 + 3] = fmaf(Aq.w, v2[s], fmaf(Bq.w, v[s], sacc[s][lq * 4 + 3]));
                }
            }
        }
    }

    // ================= Phase B: firing, normalization, norm.T store =====
#pragma unroll
    for (int s = 0; s < NS; ++s) {
        float tot = 0.0f;
#pragma unroll
        for (int l = 0; l < L; ++l) {
            float fr = __builtin_amdgcn_exp2f(sacc[s][l]) + 0.001f;
            sacc[s][l] = fr;
            tot += fr;
        }
        float inv = 1.0f / tot;
        bool ok = (n0 + s * BLK) < n_total;
#pragma unroll
        for (int l = 0; l < L; ++l) {
            float nl = sacc[s][l] * inv;
            sacc[s][l] = nl;                        // keep norm for phase C
            if (ok) out[(size_t)l * n_total + nn[s]] = nl;
        }
    }

    // compiler-only fence: keep x loads out of the high-pressure phases
    asm volatile("" ::: "memory");

    // ================= Phase C: consequents ==============================
    {
        float xv[NS][XN];
#pragma unroll
        for (int s = 0; s < NS; ++s) {
            const float4* xp = (const float4*)(x + (size_t)nn[s] * XN);
            float4 b0 = xp[0], b1 = xp[1];
            xv[s][0] = b0.x; xv[s][1] = b0.y; xv[s][2] = b0.z; xv[s][3] = b0.w;
            xv[s][4] = b1.x; xv[s][5] = b1.y; xv[s][6] = b1.z; xv[s][7] = b1.w;
        }

        float acc[NS][YN];
#pragma unroll
        for (int s = 0; s < NS; ++s)
#pragma unroll
            for (int y = 0; y < YN; ++y) acc[s][y] = 0.0f;

#pragma unroll
        for (int l = 0; l < L; ++l) {
            float t[NS][YN];
#pragma unroll
            for (int s = 0; s < NS; ++s)
#pragma unroll
                for (int y = 0; y < YN; ++y) t[s][y] = 0.0f;

#pragma unroll
            for (int i = 0; i < XN; ++i) {
                float4 wq = *(const float4*)&s_w[(l * XN + i) * YN];
#pragma unroll
                for (int s = 0; s < NS; ++s) {
                    float xs = xv[s][i];
                    t[s][0] = fmaf(xs, wq.x, t[s][0]);
                    t[s][1] = fmaf(xs, wq.y, t[s][1]);
                    t[s][2] = fmaf(xs, wq.z, t[s][2]);
                    t[s][3] = fmaf(xs, wq.w, t[s][3]);
                }
            }
#pragma unroll
            for (int s = 0; s < NS; ++s) {
                float nl = sacc[s][l];
#pragma unroll
                for (int y = 0; y < YN; ++y)
                    acc[s][y] = fmaf(nl, t[s][y], acc[s][y]);
            }
        }

        float* out_y = out + (size_t)L * n_total;
#pragma unroll
        for (int s = 0; s < NS; ++s) {
            if ((n0 + s * BLK) < n_total) {
#pragma unroll
                for (int y = 0; y < YN; ++y)
                    out_y[(size_t)y * n_total + nn[s]] = acc[s][y];
            }
        }
    }
}

extern "C" void kernel_launch(void* const* d_in, const int* in_sizes, int n_in,
                              void* d_out, int out_size, void* d_ws, size_t ws_size,
                              hipStream_t stream) {
    const float* inp = (const float*)d_in[0];
    const float* x   = (const float*)d_in[1];
    const float* c   = (const float*)d_in[2];
    const float* b   = (const float*)d_in[3];
    const float* w   = (const float*)d_in[4];
    float* out = (float*)d_out;

    int n_total = in_sizes[0] / F;   // 500000
    int grid = (n_total + BLK * NS - 1) / (BLK * NS);
    eafnn_kernel<<<grid, BLK, 0, stream>>>(inp, x, c, b, w, out, n_total);
}

// Round 4
// 393.926 us; speedup vs baseline: 1.3416x; 1.3416x over previous
//
#include <hip/hip_runtime.h>

#define F 8
#define L 16
#define XN 8
#define YN 4
#define NS 2
#define BLK 256

// out layout: [L*N] (norm.T) followed by [YN*N] (out.T)
__global__ __launch_bounds__(256) void eafnn_kernel(
    const float* __restrict__ inp,
    const float* __restrict__ x,
    const float* __restrict__ c,
    const float* __restrict__ b,
    const float* __restrict__ w,
    float* __restrict__ out,
    int n_total)
{
    // Polynomial form of the log2-domain Gaussian:
    //   k*d^2 = A*v^2 + B*v + C,  A = k = -log2(e)/(2b^2), B = -2kc, C = kc^2
    __shared__ __attribute__((aligned(16))) float s_A[F * L];
    __shared__ __attribute__((aligned(16))) float s_B[F * L];
    __shared__ __attribute__((aligned(16))) float s_Cp[F * L];
    __shared__ __attribute__((aligned(16))) float s_C0[L];
    __shared__ __attribute__((aligned(16))) float s_w[L * XN * YN];

    const int tid = threadIdx.x;
    if (tid < F * L) {
        float bb = b[tid], cc = c[tid];
        float k = -1.4426950408889634f / (2.0f * bb * bb);
        s_A[tid] = k;
        s_B[tid] = -2.0f * k * cc;
        s_Cp[tid] = k * cc * cc;
    }
    for (int i = tid; i < L * XN * YN; i += BLK) s_w[i] = w[i];
    __syncthreads();
    if (tid < L) {
        float a = 0.0f;
#pragma unroll
        for (int f = 0; f < F; ++f) a += s_Cp[f * L + tid];
        s_C0[tid] = a;
    }
    __syncthreads();

    const int n0 = blockIdx.x * (BLK * NS) + tid;

    int nn[NS];
#pragma unroll
    for (int s = 0; s < NS; ++s) {
        int n = n0 + s * BLK;
        nn[s] = (n < n_total) ? n : (n_total - 1);   // clamp loads; stores guarded
    }

    float sacc[NS][L];

    // ================= Phase A: membership accumulation =================
    {
        float fi[NS][F];
#pragma unroll
        for (int s = 0; s < NS; ++s) {
            const float4* ip = (const float4*)(inp + (size_t)nn[s] * F);
            float4 a0 = ip[0], a1 = ip[1];
            fi[s][0] = a0.x; fi[s][1] = a0.y; fi[s][2] = a0.z; fi[s][3] = a0.w;
            fi[s][4] = a1.x; fi[s][5] = a1.y; fi[s][6] = a1.z; fi[s][7] = a1.w;
        }

#pragma unroll
        for (int lq = 0; lq < L / 4; ++lq) {
            float4 cq = *(const float4*)&s_C0[lq * 4];
#pragma unroll
            for (int s = 0; s < NS; ++s) {
                sacc[s][lq * 4 + 0] = cq.x;
                sacc[s][lq * 4 + 1] = cq.y;
                sacc[s][lq * 4 + 2] = cq.z;
                sacc[s][lq * 4 + 3] = cq.w;
            }
        }

#pragma unroll
        for (int f = 0; f < F; ++f) {
            float v[NS], v2[NS];
#pragma unroll
            for (int s = 0; s < NS; ++s) { v[s] = fi[s][f]; v2[s] = v[s] * v[s]; }
#pragma unroll
            for (int lq = 0; lq < L / 4; ++lq) {
                float4 Aq = *(const float4*)&s_A[f * L + lq * 4];
                float4 Bq = *(const float4*)&s_B[f * L + lq * 4];
#pragma unroll
                for (int s = 0; s < NS; ++s) {
                    sacc[s][lq * 4 + 0] = fmaf(Aq.x, v2[s], fmaf(Bq.x, v[s], sacc[s][lq * 4 + 0]));
                    sacc[s][lq * 4 + 1] = fmaf(Aq.y, v2[s], fmaf(Bq.y, v[s], sacc[s][lq * 4 + 1]));
                    sacc[s][lq * 4 + 2] = fmaf(Aq.z, v2[s], fmaf(Bq.z, v[s], sacc[s][lq * 4 + 2]));
                    sacc[s][lq * 4 + 3] = fmaf(Aq.w, v2[s], fmaf(Bq.w, v[s], sacc[s][lq * 4 + 3]));
                }
            }
        }
    }

    // ================= Phase B: firing, normalization, norm.T store =====
#pragma unroll
    for (int s = 0; s < NS; ++s) {
        float tot = 0.0f;
#pragma unroll
        for (int l = 0; l < L; ++l) {
            float fr = __builtin_amdgcn_exp2f(sacc[s][l]) + 0.001f;
            sacc[s][l] = fr;
            tot += fr;
        }
        float inv = 1.0f / tot;
        bool ok = (n0 + s * BLK) < n_total;
#pragma unroll
        for (int l = 0; l < L; ++l) {
            float nl = sacc[s][l] * inv;
            sacc[s][l] = nl;                        // keep norm for phase C
            if (ok) out[(size_t)l * n_total + nn[s]] = nl;
        }
    }

    // compiler-only fence: keep x loads out of the high-pressure phases
    asm volatile("" ::: "memory");

    // ================= Phase C: consequents ==============================
    {
        float xv[NS][XN];
#pragma unroll
        for (int s = 0; s < NS; ++s) {
            const float4* xp = (const float4*)(x + (size_t)nn[s] * XN);
            float4 b0 = xp[0], b1 = xp[1];
            xv[s][0] = b0.x; xv[s][1] = b0.y; xv[s][2] = b0.z; xv[s][3] = b0.w;
            xv[s][4] = b1.x; xv[s][5] = b1.y; xv[s][6] = b1.z; xv[s][7] = b1.w;
        }

        float acc[NS][YN];
#pragma unroll
        for (int s = 0; s < NS; ++s)
#pragma unroll
            for (int y = 0; y < YN; ++y) acc[s][y] = 0.0f;

#pragma unroll
        for (int l = 0; l < L; ++l) {
            float t[NS][YN];
#pragma unroll
            for (int s = 0; s < NS; ++s)
#pragma unroll
                for (int y = 0; y < YN; ++y) t[s][y] = 0.0f;

#pragma unroll
            for (int i = 0; i < XN; ++i) {
                float4 wq = *(const float4*)&s_w[(l * XN + i) * YN];
#pragma unroll
                for (int s = 0; s < NS; ++s) {
                    float xs = xv[s][i];
                    t[s][0] = fmaf(xs, wq.x, t[s][0]);
                    t[s][1] = fmaf(xs, wq.y, t[s][1]);
                    t[s][2] = fmaf(xs, wq.z, t[s][2]);
                    t[s][3] = fmaf(xs, wq.w, t[s][3]);
                }
            }
#pragma unroll
            for (int s = 0; s < NS; ++s) {
                float nl = sacc[s][l];
#pragma unroll
                for (int y = 0; y < YN; ++y)
                    acc[s][y] = fmaf(nl, t[s][y], acc[s][y]);
            }
        }

        float* out_y = out + (size_t)L * n_total;
#pragma unroll
        for (int s = 0; s < NS; ++s) {
            if ((n0 + s * BLK) < n_total) {
#pragma unroll
                for (int y = 0; y < YN; ++y)
                    out_y[(size_t)y * n_total + nn[s]] = acc[s][y];
            }
        }
    }
}

extern "C" void kernel_launch(void* const* d_in, const int* in_sizes, int n_in,
                              void* d_out, int out_size, void* d_ws, size_t ws_size,
                              hipStream_t stream) {
    const float* inp = (const float*)d_in[0];
    const float* x   = (const float*)d_in[1];
    const float* c   = (const float*)d_in[2];
    const float* b   = (const float*)d_in[3];
    const float* w   = (const float*)d_in[4];
    float* out = (float*)d_out;

    int n_total = in_sizes[0] / F;   // 500000
    int grid = (n_total + BLK * NS - 1) / (BLK * NS);
    eafnn_kernel<<<grid, BLK, 0, stream>>>(inp, x, c, b, w, out, n_total);
}

// Round 5
// 22.282 us; speedup vs baseline: 23.7182x; 17.6791x over previous
//
#include <hip/hip_runtime.h>

#define F 8
#define L 16
#define XN 8
#define YN 4
#define BLK 256

// out layout: [L*N] (norm.T) followed by [YN*N] (out.T)
__global__ __launch_bounds__(256) void eafnn_kernel(
    const float* __restrict__ inp,
    const float* __restrict__ x,
    const float* __restrict__ c,
    const float* __restrict__ b,
    const float* __restrict__ w,
    float* __restrict__ out,
    int n_total)
{
    // Derived tables (need per-block rcp) in LDS.
    // k*d^2 = A*v^2 + B*v + C,  A = k = -log2(e)/(2b^2), B = -2kc, C0[l] = sum_f k c^2
    __shared__ __attribute__((aligned(16))) float s_A[F * L];
    __shared__ __attribute__((aligned(16))) float s_B[F * L];
    __shared__ __attribute__((aligned(16))) float s_Cp[F * L];
    __shared__ __attribute__((aligned(16))) float s_C0[L];

    const int tid = threadIdx.x;
    if (tid < F * L) {
        float bb = b[tid], cc = c[tid];
        float k = -1.4426950408889634f / (2.0f * bb * bb);
        s_A[tid] = k;
        s_B[tid] = -2.0f * k * cc;
        s_Cp[tid] = k * cc * cc;
    }
    __syncthreads();
    if (tid < L) {
        float a = 0.0f;
#pragma unroll
        for (int f = 0; f < F; ++f) a += s_Cp[f * L + tid];
        s_C0[tid] = a;
    }
    __syncthreads();

    int n = blockIdx.x * BLK + tid;
    const bool ok = (n < n_total);
    if (!ok) n = n_total - 1;            // clamp loads; stores guarded

    // ---- coalesced per-sample inputs ----
    const float4* ip = (const float4*)(inp + (size_t)n * F);
    float4 a0 = ip[0], a1 = ip[1];
    float fi[F] = {a0.x, a0.y, a0.z, a0.w, a1.x, a1.y, a1.z, a1.w};

    const float4* xp = (const float4*)(x + (size_t)n * XN);
    float4 x0 = xp[0], x1 = xp[1];
    float xv[XN] = {x0.x, x0.y, x0.z, x0.w, x1.x, x1.y, x1.z, x1.w};

    // ---- membership accumulation in log2 domain (LDS tables) ----
    float sacc[L];
#pragma unroll
    for (int lq = 0; lq < L / 4; ++lq) {
        float4 cq = *(const float4*)&s_C0[lq * 4];
        sacc[lq * 4 + 0] = cq.x;
        sacc[lq * 4 + 1] = cq.y;
        sacc[lq * 4 + 2] = cq.z;
        sacc[lq * 4 + 3] = cq.w;
    }

#pragma unroll
    for (int f = 0; f < F; ++f) {
        float v = fi[f];
        float v2 = v * v;
#pragma unroll
        for (int lq = 0; lq < L / 4; ++lq) {
            float4 Aq = *(const float4*)&s_A[f * L + lq * 4];
            float4 Bq = *(const float4*)&s_B[f * L + lq * 4];
            sacc[lq * 4 + 0] = fmaf(Aq.x, v2, fmaf(Bq.x, v, sacc[lq * 4 + 0]));
            sacc[lq * 4 + 1] = fmaf(Aq.y, v2, fmaf(Bq.y, v, sacc[lq * 4 + 1]));
            sacc[lq * 4 + 2] = fmaf(Aq.z, v2, fmaf(Bq.z, v, sacc[lq * 4 + 2]));
            sacc[lq * 4 + 3] = fmaf(Aq.w, v2, fmaf(Bq.w, v, sacc[lq * 4 + 3]));
        }
    }

    // ---- firing + normalization + norm.T store ----
    float tot = 0.0f;
#pragma unroll
    for (int l = 0; l < L; ++l) {
        float fr = __builtin_amdgcn_exp2f(sacc[l]) + 0.001f;
        sacc[l] = fr;
        tot += fr;
    }
    float inv = 1.0f / tot;
#pragma unroll
    for (int l = 0; l < L; ++l) {
        float nl = sacc[l] * inv;
        sacc[l] = nl;                               // keep norm
        if (ok) out[(size_t)l * n_total + n] = nl;  // coalesced per l
    }

    // ---- consequents: w read DIRECT from global with wave-uniform address ----
    // (compiler selects scalar s_load path; worst case L1-broadcast vector load)
    float acc[YN] = {0.f, 0.f, 0.f, 0.f};
#pragma unroll
    for (int l = 0; l < L; ++l) {
        float t0 = 0.f, t1 = 0.f, t2 = 0.f, t3 = 0.f;
#pragma unroll
        for (int i = 0; i < XN; ++i) {
            float4 wq = *(const float4*)&w[(l * XN + i) * YN];  // uniform addr
            float xs = xv[i];
            t0 = fmaf(xs, wq.x, t0);
            t1 = fmaf(xs, wq.y, t1);
            t2 = fmaf(xs, wq.z, t2);
            t3 = fmaf(xs, wq.w, t3);
        }
        float nl = sacc[l];
        acc[0] = fmaf(nl, t0, acc[0]);
        acc[1] = fmaf(nl, t1, acc[1]);
        acc[2] = fmaf(nl, t2, acc[2]);
        acc[3] = fmaf(nl, t3, acc[3]);
    }

    float* out_y = out + (size_t)L * n_total;
    if (ok) {
#pragma unroll
        for (int y = 0; y < YN; ++y)
            out_y[(size_t)y * n_total + n] = acc[y];  // coalesced per y
    }
}

extern "C" void kernel_launch(void* const* d_in, const int* in_sizes, int n_in,
                              void* d_out, int out_size, void* d_ws, size_t ws_size,
                              hipStream_t stream) {
    const float* inp = (const float*)d_in[0];
    const float* x   = (const float*)d_in[1];
    const float* c   = (const float*)d_in[2];
    const float* b   = (const float*)d_in[3];
    const float* w   = (const float*)d_in[4];
    float* out = (float*)d_out;

    int n_total = in_sizes[0] / F;   // 500000
    int grid = (n_total + BLK - 1) / BLK;
    eafnn_kernel<<<grid, BLK, 0, stream>>>(inp, x, c, b, w, out, n_total);
}